// Round 1
// baseline (699.050 us; speedup 1.0000x reference)
//
#include <hip/hip_runtime.h>

#define NB   4096
#define NIN  1024
#define NH   2048
#define NOUT 1024
#define NH4  8192   // 4*NH

typedef short short8 __attribute__((ext_vector_type(8)));
typedef float f32x4 __attribute__((ext_vector_type(4)));
typedef unsigned short ushort4v __attribute__((ext_vector_type(4)));
typedef unsigned short ushort8v __attribute__((ext_vector_type(8)));

__device__ __forceinline__ float bf2f(unsigned short u) {
  union { unsigned int i; float f; } c; c.i = ((unsigned int)u) << 16; return c.f;
}
__device__ __forceinline__ unsigned short f2bf(float f) {
  union { float f; unsigned int i; } c; c.f = f;
  unsigned int u = c.i;
  u += 0x7FFFu + ((u >> 16) & 1u);   // RNE; inputs are finite
  return (unsigned short)(u >> 16);
}
__device__ __forceinline__ float sigf(float x) { return 1.0f / (1.0f + __expf(-x)); }
__device__ __forceinline__ float tanh_f(float x) { return 1.0f - 2.0f / (__expf(2.0f * x) + 1.0f); }

// ---------------- fp32 -> bf16 conversion ----------------
__global__ __launch_bounds__(256) void f2b_kernel(const float* __restrict__ s,
                                                  unsigned short* __restrict__ d, int n) {
  int i = (blockIdx.x * 256 + threadIdx.x) * 4;
  if (i >= n) return;
  float4 v = *(const float4*)(s + i);
  ushort4v o;
  o.x = f2bf(v.x); o.y = f2bf(v.y); o.z = f2bf(v.z); o.w = f2bf(v.w);
  *(ushort4v*)(d + i) = o;
}

// ---------------- async global->LDS, 16B/lane ----------------
__device__ __forceinline__ void gload16(const void* g, void* l) {
  __builtin_amdgcn_global_load_lds((const __attribute__((address_space(1))) void*)g,
                                   (__attribute__((address_space(3))) void*)l, 16, 0, 0);
}

// ---------------- NT GEMM: C[m][n] = sum_k A[m][k]*B[n][k] + bias[n] ----------------
// A: MxK bf16, B: NxK bf16 (row-major, K contiguous). Output fp32 (Cf) or bf16 (Cb).
// M,N multiples of 128; K multiple of 32. 128x128 block tile, 4 waves, 64x64/wave.
__global__ __launch_bounds__(256) void gemm_bt(const unsigned short* __restrict__ A,
                                               const unsigned short* __restrict__ Bm,
                                               const float* __restrict__ bias,
                                               float* __restrict__ Cf,
                                               unsigned short* __restrict__ Cb,
                                               int M, int N, int K) {
  __shared__ __align__(16) unsigned short As[128 * 32];
  __shared__ __align__(16) unsigned short Bs[128 * 32];
  const int t = threadIdx.x;
  const int w = t >> 6;
  const int lane = t & 63;
  const int m0 = blockIdx.y * 128;
  const int n0 = blockIdx.x * 128;
  const int wm = (w >> 1) * 64;
  const int wn = (w & 1) * 64;

  f32x4 acc[4][4];
#pragma unroll
  for (int i = 0; i < 4; i++)
#pragma unroll
    for (int j = 0; j < 4; j++) { f32x4 z = {0.f, 0.f, 0.f, 0.f}; acc[i][j] = z; }

  // staging: thread t covers row t>>2 (0..63), cols (t&3)*8 .. +8 of the k-tile
  const int srow = t >> 2;
  const int scol = (t & 3) * 8;
  const unsigned short* Ag = A + (size_t)(m0 + srow) * K + scol;
  const unsigned short* Bg = Bm + (size_t)(n0 + srow) * K + scol;
  const size_t rowStep = (size_t)64 * K;
  // wave-uniform LDS bases: wave w writes elems [w*512, w*512+512) (issue 0) / +2048 (issue 1)
  unsigned short* AsW0 = As + w * 512;
  unsigned short* AsW1 = As + 2048 + w * 512;
  unsigned short* BsW0 = Bs + w * 512;
  unsigned short* BsW1 = Bs + 2048 + w * 512;

  const int fr = lane & 15;          // m (A) / n (B) index within 16
  const int fk = (lane >> 4) * 8;    // k base within 32

  for (int k0 = 0; k0 < K; k0 += 32) {
    gload16(Ag + k0, AsW0);
    gload16(Ag + rowStep + k0, AsW1);
    gload16(Bg + k0, BsW0);
    gload16(Bg + rowStep + k0, BsW1);
    __syncthreads();   // compiler drains vmcnt before s_barrier

    short8 af[4], bfr[4];
#pragma unroll
    for (int i = 0; i < 4; i++) af[i] = *(const short8*)&As[(wm + i * 16 + fr) * 32 + fk];
#pragma unroll
    for (int j = 0; j < 4; j++) bfr[j] = *(const short8*)&Bs[(wn + j * 16 + fr) * 32 + fk];
#pragma unroll
    for (int i = 0; i < 4; i++)
#pragma unroll
      for (int j = 0; j < 4; j++)
        acc[i][j] = __builtin_amdgcn_mfma_f32_16x16x32_bf16(af[i], bfr[j], acc[i][j], 0, 0, 0);
    __syncthreads();
  }

  // epilogue: C/D layout col=lane&15, row=(lane>>4)*4+reg   [measured m89/m91]
  const int cn = lane & 15;
  const int cm = (lane >> 4) * 4;
#pragma unroll
  for (int i = 0; i < 4; i++) {
#pragma unroll
    for (int j = 0; j < 4; j++) {
      const int col = n0 + wn + j * 16 + cn;
      const float bv = bias ? bias[col] : 0.0f;
      const size_t base = (size_t)(m0 + wm + i * 16 + cm) * N + col;
#pragma unroll
      for (int r = 0; r < 4; r++) {
        const float v = acc[i][j][r] + bv;
        if (Cf) Cf[base + (size_t)r * N] = v;
        else    Cb[base + (size_t)r * N] = f2bf(v);
      }
    }
  }
}

// ---------------- fused LN(zx)+LN(zh) -> gates -> cx -> LN(cx) -> hx ----------------
// One block per batch row. 256 threads x 8 contiguous cols each (H=2048).
// Zx,Zh: B x 4H bf16 (gate order f,i,c,o). Writes hx,cx (fp32, into d_out) + hx bf16.
__global__ __launch_bounds__(256) void ln_gates(const unsigned short* __restrict__ Zx,
                                                const unsigned short* __restrict__ Zh,
                                                const float* __restrict__ c0,
                                                const float* __restrict__ ax, const float* __restrict__ bx,
                                                const float* __restrict__ ah, const float* __restrict__ bh,
                                                const float* __restrict__ ac, const float* __restrict__ bc,
                                                float* __restrict__ out_top,
                                                unsigned short* __restrict__ hx_bf) {
  const int b = blockIdx.x;
  const int t = threadIdx.x;
  const int n = t * 8;
  const int w = t >> 6;
  const int lane = t & 63;
  const float inv_n = 1.0f / 2048.0f, inv_nm1 = 1.0f / 2047.0f;

  short8 zx[4], zh[4];
  const size_t rowoff = (size_t)b * NH4;
#pragma unroll
  for (int g = 0; g < 4; g++) {
    zx[g] = *(const short8*)(Zx + rowoff + g * NH + n);
    zh[g] = *(const short8*)(Zh + rowoff + g * NH + n);
  }

  float s[16];
#pragma unroll
  for (int g = 0; g < 4; g++) {
    float su = 0, sq = 0, su2 = 0, sq2 = 0;
#pragma unroll
    for (int j = 0; j < 8; j++) {
      float v = bf2f((unsigned short)zx[g][j]); su += v; sq += v * v;
      float u = bf2f((unsigned short)zh[g][j]); su2 += u; sq2 += u * u;
    }
    s[g * 4 + 0] = su; s[g * 4 + 1] = sq; s[g * 4 + 2] = su2; s[g * 4 + 3] = sq2;
  }
#pragma unroll
  for (int i = 0; i < 16; i++) {
    float v = s[i];
#pragma unroll
    for (int o = 32; o > 0; o >>= 1) v += __shfl_xor(v, o, 64);
    s[i] = v;
  }
  __shared__ float red[4][16];
  __shared__ float red2[4][2];
  if (lane == 0) {
#pragma unroll
    for (int i = 0; i < 16; i++) red[w][i] = s[i];
  }
  __syncthreads();
#pragma unroll
  for (int i = 0; i < 16; i++) s[i] = red[0][i] + red[1][i] + red[2][i] + red[3][i];

  float mux[4], ivx[4], muh[4], ivh[4];
#pragma unroll
  for (int g = 0; g < 4; g++) {
    mux[g] = s[g * 4 + 0] * inv_n;
    float vx = fmaxf((s[g * 4 + 1] - s[g * 4 + 0] * mux[g]) * inv_nm1, 0.0f);
    ivx[g] = 1.0f / (sqrtf(vx) + 1e-5f);
    muh[g] = s[g * 4 + 2] * inv_n;
    float vh = fmaxf((s[g * 4 + 3] - s[g * 4 + 2] * muh[g]) * inv_nm1, 0.0f);
    ivh[g] = 1.0f / (sqrtf(vh) + 1e-5f);
  }

  float axl[8], bxl[8], ahl[8], bhl[8], c0l[8];
  *(float4*)&axl[0] = *(const float4*)(ax + n); *(float4*)&axl[4] = *(const float4*)(ax + n + 4);
  *(float4*)&bxl[0] = *(const float4*)(bx + n); *(float4*)&bxl[4] = *(const float4*)(bx + n + 4);
  *(float4*)&ahl[0] = *(const float4*)(ah + n); *(float4*)&ahl[4] = *(const float4*)(ah + n + 4);
  *(float4*)&bhl[0] = *(const float4*)(bh + n); *(float4*)&bhl[4] = *(const float4*)(bh + n + 4);
  const float* c0p = c0 + (size_t)b * NH + n;
  *(float4*)&c0l[0] = *(const float4*)(c0p); *(float4*)&c0l[4] = *(const float4*)(c0p + 4);

  float cx[8], og[8];
  float cs = 0, css = 0;
#pragma unroll
  for (int j = 0; j < 8; j++) {
    float pre[4];
#pragma unroll
    for (int g = 0; g < 4; g++) {
      float vx = bf2f((unsigned short)zx[g][j]);
      float vh = bf2f((unsigned short)zh[g][j]);
      pre[g] = ((vx - mux[g]) * ivx[g]) * axl[j] + bxl[j]
             + ((vh - muh[g]) * ivh[g]) * ahl[j] + bhl[j];
    }
    float fg = sigf(pre[0]);
    float ig = sigf(pre[1]);
    float ct = tanh_f(pre[2]);
    og[j] = sigf(pre[3]);
    float c = fg * c0l[j] + ig * ct;
    cx[j] = c; cs += c; css += c * c;
  }
#pragma unroll
  for (int o = 32; o > 0; o >>= 1) { cs += __shfl_xor(cs, o, 64); css += __shfl_xor(css, o, 64); }
  if (lane == 0) { red2[w][0] = cs; red2[w][1] = css; }
  __syncthreads();
  cs = red2[0][0] + red2[1][0] + red2[2][0] + red2[3][0];
  css = red2[0][1] + red2[1][1] + red2[2][1] + red2[3][1];
  const float muc = cs * inv_n;
  const float varc = fmaxf((css - cs * muc) * inv_nm1, 0.0f);
  const float ivc = 1.0f / (sqrtf(varc) + 1e-5f);

  float acl[8], bcl[8];
  *(float4*)&acl[0] = *(const float4*)(ac + n); *(float4*)&acl[4] = *(const float4*)(ac + n + 4);
  *(float4*)&bcl[0] = *(const float4*)(bc + n); *(float4*)&bcl[4] = *(const float4*)(bc + n + 4);

  float hx[8];
#pragma unroll
  for (int j = 0; j < 8; j++)
    hx[j] = og[j] * tanh_f((cx[j] - muc) * ivc * acl[j] + bcl[j]);

  // outputs: d_out = [out(B,OUT) | hx(B,H) | cx(B,H)]
  float* hx_out = out_top + (size_t)NB * NOUT + (size_t)b * NH + n;
  float* cx_out = out_top + (size_t)NB * NOUT + (size_t)NB * NH + (size_t)b * NH + n;
  float4 v;
  v.x = hx[0]; v.y = hx[1]; v.z = hx[2]; v.w = hx[3]; *(float4*)(hx_out) = v;
  v.x = hx[4]; v.y = hx[5]; v.z = hx[6]; v.w = hx[7]; *(float4*)(hx_out + 4) = v;
  v.x = cx[0]; v.y = cx[1]; v.z = cx[2]; v.w = cx[3]; *(float4*)(cx_out) = v;
  v.x = cx[4]; v.y = cx[5]; v.z = cx[6]; v.w = cx[7]; *(float4*)(cx_out + 4) = v;
  ushort8v hb;
#pragma unroll
  for (int j = 0; j < 8; j++) hb[j] = f2bf(hx[j]);
  *(ushort8v*)(hx_bf + (size_t)b * NH + n) = hb;
}

extern "C" void kernel_launch(void* const* d_in, const int* in_sizes, int n_in,
                              void* d_out, int out_size, void* d_ws, size_t ws_size,
                              hipStream_t stream) {
  const float* inp = (const float*)d_in[0];
  const float* h0  = (const float*)d_in[1];
  const float* c0  = (const float*)d_in[2];
  const float* Whg[4] = {(const float*)d_in[3], (const float*)d_in[5], (const float*)d_in[7], (const float*)d_in[9]};
  const float* bhg[4] = {(const float*)d_in[4], (const float*)d_in[6], (const float*)d_in[8], (const float*)d_in[10]};
  const float* Wxg[4] = {(const float*)d_in[11], (const float*)d_in[13], (const float*)d_in[15], (const float*)d_in[17]};
  const float* bxg[4] = {(const float*)d_in[12], (const float*)d_in[14], (const float*)d_in[16], (const float*)d_in[18]};
  const float* Wdec = (const float*)d_in[19];
  const float* bdec = (const float*)d_in[20];
  const float* ax = (const float*)d_in[21];
  const float* bx = (const float*)d_in[22];
  const float* ah = (const float*)d_in[23];
  const float* bh = (const float*)d_in[24];
  const float* ac = (const float*)d_in[25];
  const float* bc = (const float*)d_in[26];

  // workspace carve (~222 MB)
  char* p = (char*)d_ws;
  auto take = [&](size_t bytes) -> void* {
    void* r = (void*)p;
    p += (bytes + 255) & ~(size_t)255;
    return r;
  };
  unsigned short* Xb   = (unsigned short*)take((size_t)NB * NIN * 2);
  unsigned short* H0b  = (unsigned short*)take((size_t)NB * NH * 2);
  unsigned short* HXb  = (unsigned short*)take((size_t)NB * NH * 2);
  unsigned short* Wx4b = (unsigned short*)take((size_t)NH4 * NIN * 2);
  unsigned short* Wh4b = (unsigned short*)take((size_t)NH4 * NH * 2);
  unsigned short* Wdb  = (unsigned short*)take((size_t)NOUT * NH * 2);
  float* bx4 = (float*)take((size_t)NH4 * 4);
  float* bh4 = (float*)take((size_t)NH4 * 4);
  unsigned short* Zx = (unsigned short*)take((size_t)NB * NH4 * 2);
  unsigned short* Zh = (unsigned short*)take((size_t)NB * NH4 * 2);

  auto cv = [&](const float* s, unsigned short* d, size_t n) {
    f2b_kernel<<<dim3((unsigned)((n + 1023) / 1024)), dim3(256), 0, stream>>>(s, d, (int)n);
  };
  cv(inp, Xb, (size_t)NB * NIN);
  cv(h0, H0b, (size_t)NB * NH);
  for (int g = 0; g < 4; g++) {
    cv(Wxg[g], Wx4b + (size_t)g * NH * NIN, (size_t)NH * NIN);
    cv(Whg[g], Wh4b + (size_t)g * NH * NH, (size_t)NH * NH);
    hipMemcpyAsync(bx4 + g * NH, bxg[g], NH * sizeof(float), hipMemcpyDeviceToDevice, stream);
    hipMemcpyAsync(bh4 + g * NH, bhg[g], NH * sizeof(float), hipMemcpyDeviceToDevice, stream);
  }
  cv(Wdec, Wdb, (size_t)NOUT * NH);

  // Zx = inp @ Wx4^T + bx4   (M=4096, N=8192, K=1024) -> bf16
  gemm_bt<<<dim3(NH4 / 128, NB / 128), 256, 0, stream>>>(Xb, Wx4b, bx4, nullptr, Zx, NB, NH4, NIN);
  // Zh = h0 @ Wh4^T + bh4    (M=4096, N=8192, K=2048) -> bf16
  gemm_bt<<<dim3(NH4 / 128, NB / 128), 256, 0, stream>>>(H0b, Wh4b, bh4, nullptr, Zh, NB, NH4, NH);
  // fused LN + gates -> hx, cx (fp32 into d_out) + hx bf16
  ln_gates<<<dim3(NB), 256, 0, stream>>>(Zx, Zh, c0, ax, bx, ah, bh, ac, bc, (float*)d_out, HXb);
  // out = hx @ Wdec^T + bdec (M=4096, N=1024, K=2048) -> fp32 into d_out[0:B*OUT)
  gemm_bt<<<dim3(NOUT / 128, NB / 128), 256, 0, stream>>>(HXb, Wdb, bdec, (float*)d_out, nullptr, NB, NOUT, NH);
}

// Round 2
// 612.596 us; speedup vs baseline: 1.1411x; 1.1411x over previous
//
#include <hip/hip_runtime.h>

#define NB   4096
#define NIN  1024
#define NH   2048
#define NOUT 1024
#define NH4  8192   // 4*NH

typedef short short8 __attribute__((ext_vector_type(8)));
typedef float f32x4 __attribute__((ext_vector_type(4)));
typedef unsigned short ushort8v __attribute__((ext_vector_type(8)));

__device__ __forceinline__ float bf2f(unsigned short u) {
  union { unsigned int i; float f; } c; c.i = ((unsigned int)u) << 16; return c.f;
}
__device__ __forceinline__ unsigned short f2bf(float f) {
  union { float f; unsigned int i; } c; c.f = f;
  unsigned int u = c.i;
  u += 0x7FFFu + ((u >> 16) & 1u);   // RNE; inputs are finite
  return (unsigned short)(u >> 16);
}
__device__ __forceinline__ float sigf(float x) { return 1.0f / (1.0f + __expf(-x)); }
__device__ __forceinline__ float tanh_f(float x) { return 1.0f - 2.0f / (__expf(2.0f * x) + 1.0f); }

// ---------------- workspace layout (ushort elems), compile-time ----------------
#define CNT_INP  ((size_t)NB * NIN)        // 4,194,304
#define CNT_H0   ((size_t)NB * NH)         // 8,388,608
#define CNT_WXG  ((size_t)NH * NIN)        // 2,097,152 per gate
#define CNT_WHG  ((size_t)NH * NH)         // 4,194,304 per gate
#define CNT_WD   ((size_t)NOUT * NH)       // 2,097,152
#define OFF_XB   ((size_t)0)
#define OFF_H0B  (OFF_XB + CNT_INP)
#define OFF_HXB  (OFF_H0B + CNT_H0)
#define OFF_WX   (OFF_HXB + CNT_H0)
#define OFF_WH   (OFF_WX + 4 * CNT_WXG)
#define OFF_WD   (OFF_WH + 4 * CNT_WHG)
#define OFF_ZX   (OFF_WD + CNT_WD)
#define OFF_ZH   (OFF_ZX + (size_t)NB * NH4)
#define CVT_TOTAL (OFF_WD + CNT_WD)        // everything before Zx gets converted

// ---------------- single fused fp32->bf16 convert over all 11 segments ----------------
struct CvtArgs { const float* src[11]; };

__global__ __launch_bounds__(256) void cvt_all(CvtArgs a, unsigned short* __restrict__ dstBase) {
  const size_t i = ((size_t)blockIdx.x * 256 + threadIdx.x) * 8;
  if (i >= CVT_TOTAL) return;
  // segment order: inp, h0, Wx0..3, Wh0..3, Wdec (boundaries all multiples of 2048)
  const size_t cnt[11] = {CNT_INP, CNT_H0, CNT_WXG, CNT_WXG, CNT_WXG, CNT_WXG,
                          CNT_WHG, CNT_WHG, CNT_WHG, CNT_WHG, CNT_WD};
  const size_t dst[11] = {OFF_XB, OFF_H0B,
                          OFF_WX, OFF_WX + CNT_WXG, OFF_WX + 2 * CNT_WXG, OFF_WX + 3 * CNT_WXG,
                          OFF_WH, OFF_WH + CNT_WHG, OFF_WH + 2 * CNT_WHG, OFF_WH + 3 * CNT_WHG,
                          OFF_WD};
  size_t base = 0;
#pragma unroll
  for (int s = 0; s < 11; s++) {
    if (i < base + cnt[s]) {
      const size_t off = i - base;
      const float* sp = a.src[s] + off;
      float4 v0 = *(const float4*)(sp);
      float4 v1 = *(const float4*)(sp + 4);
      ushort8v o;
      o[0] = f2bf(v0.x); o[1] = f2bf(v0.y); o[2] = f2bf(v0.z); o[3] = f2bf(v0.w);
      o[4] = f2bf(v1.x); o[5] = f2bf(v1.y); o[6] = f2bf(v1.z); o[7] = f2bf(v1.w);
      *(ushort8v*)(dstBase + dst[s] + off) = o;
      return;
    }
    base += cnt[s];
  }
}

// ---------------- async global->LDS, 16B/lane ----------------
__device__ __forceinline__ void gload16(const void* g, void* l) {
  __builtin_amdgcn_global_load_lds((const __attribute__((address_space(1))) void*)g,
                                   (__attribute__((address_space(3))) void*)l, 16, 0, 0);
}

// ---------------- NT GEMM core: C[m][n] = sum_k A[m][k]*B[n][k] + bias[n] ----------------
// MF = m-fragments per wave (4 -> 128-row tile, 2 -> 64-row tile). N-tile fixed 128.
// XOR swizzle: LDS slot (row, s) holds global k-block (s ^ ((row>>1)&3)) -> bank-conflict-free
// fragment reads (2-way max, free per m136). Staging coalescing unchanged (per-row permutation).
template<int MF, bool BOUT>
__device__ __forceinline__ void gemm_core(const unsigned short* __restrict__ A,
                                          const unsigned short* __restrict__ Bm,
                                          const float* b0p, const float* b1p,
                                          const float* b2p, const float* b3p,
                                          float* __restrict__ Cf, unsigned short* __restrict__ Cb,
                                          int N, int K) {
  constexpr int TM = MF * 32;
  __shared__ __align__(16) unsigned short As[TM * 32];
  __shared__ __align__(16) unsigned short Bs[128 * 32];
  const int t = threadIdx.x;
  const int w = t >> 6;
  const int lane = t & 63;
  const int m0 = blockIdx.y * TM;
  const int n0 = blockIdx.x * 128;
  const int wm = (w >> 1) * (MF * 16);
  const int wn = (w & 1) * 64;

  f32x4 acc[MF][4];
#pragma unroll
  for (int i = 0; i < MF; i++)
#pragma unroll
    for (int j = 0; j < 4; j++) { f32x4 z = {0.f, 0.f, 0.f, 0.f}; acc[i][j] = z; }

  // staging: thread t covers row t>>2 (0..63) of the 64-row issue group; k-block XOR-swizzled
  const int srow = t >> 2;
  const int scb = (t & 3) ^ ((srow >> 1) & 3);
  const unsigned short* Ag = A + (size_t)(m0 + srow) * K + scb * 8;
  const unsigned short* Bg = Bm + (size_t)(n0 + srow) * K + scb * 8;
  const size_t rowStep = (size_t)64 * K;
  unsigned short* AsW0 = As + w * 512;
  unsigned short* AsW1 = (MF == 4) ? (As + 2048 + w * 512) : (As + w * 512);
  unsigned short* BsW0 = Bs + w * 512;
  unsigned short* BsW1 = Bs + 2048 + w * 512;

  const int fr = lane & 15;                                   // m/n index within 16
  const int fks = (((lane >> 4) ^ ((fr >> 1) & 3)) & 3) * 8;  // swizzled k-slot (indep. of frag idx)

  for (int k0 = 0; k0 < K; k0 += 32) {
    gload16(Ag + k0, AsW0);
    if (MF == 4) gload16(Ag + rowStep + k0, AsW1);
    gload16(Bg + k0, BsW0);
    gload16(Bg + rowStep + k0, BsW1);
    __syncthreads();

    short8 af[MF], bfr[4];
#pragma unroll
    for (int i = 0; i < MF; i++) af[i] = *(const short8*)&As[(wm + i * 16 + fr) * 32 + fks];
#pragma unroll
    for (int j = 0; j < 4; j++) bfr[j] = *(const short8*)&Bs[(wn + j * 16 + fr) * 32 + fks];
#pragma unroll
    for (int i = 0; i < MF; i++)
#pragma unroll
      for (int j = 0; j < 4; j++)
        acc[i][j] = __builtin_amdgcn_mfma_f32_16x16x32_bf16(af[i], bfr[j], acc[i][j], 0, 0, 0);
    __syncthreads();
  }

  // epilogue: C/D layout col=lane&15, row=(lane>>4)*4+reg   [measured m89/m91]
  const int cn = lane & 15;
  const int cm = (lane >> 4) * 4;
#pragma unroll
  for (int i = 0; i < MF; i++) {
#pragma unroll
    for (int j = 0; j < 4; j++) {
      const int col = n0 + wn + j * 16 + cn;
      const float* bp = (col < 2048) ? b0p : ((col < 4096) ? b1p : ((col < 6144) ? b2p : b3p));
      const float bv = bp[col & 2047];
      const size_t base = (size_t)(m0 + wm + i * 16 + cm) * N + col;
#pragma unroll
      for (int r = 0; r < 4; r++) {
        const float v = acc[i][j][r] + bv;
        if (BOUT) Cb[base + (size_t)r * N] = f2bf(v);
        else      Cf[base + (size_t)r * N] = v;
      }
    }
  }
}

// Zx and Zh fused in one grid (z=0: x-side K=1024, z=1: h-side K=2048) for tail overlap.
__global__ __launch_bounds__(256) void gemm_dual(const unsigned short* __restrict__ Xb,
                                                 const unsigned short* __restrict__ Wx,
                                                 const unsigned short* __restrict__ H0b,
                                                 const unsigned short* __restrict__ Wh,
                                                 const float* bx0, const float* bx1,
                                                 const float* bx2, const float* bx3,
                                                 const float* bh0, const float* bh1,
                                                 const float* bh2, const float* bh3,
                                                 unsigned short* __restrict__ Zx,
                                                 unsigned short* __restrict__ Zh) {
  if (blockIdx.z == 0)
    gemm_core<4, true>(Xb, Wx, bx0, bx1, bx2, bx3, nullptr, Zx, NH4, NIN);
  else
    gemm_core<4, true>(H0b, Wh, bh0, bh1, bh2, bh3, nullptr, Zh, NH4, NH);
}

// decoder: 64x128 tile -> 512 blocks (2/CU) instead of 256 (1/CU at 128x128)
__global__ __launch_bounds__(256) void gemm_dec(const unsigned short* __restrict__ HXb,
                                                const unsigned short* __restrict__ Wd,
                                                const float* __restrict__ bdec,
                                                float* __restrict__ out) {
  gemm_core<2, false>(HXb, Wd, bdec, bdec, bdec, bdec, out, nullptr, NOUT, NH);
}

// ---------------- fused LN(zx)+LN(zh) -> gates -> cx -> LN(cx) -> hx ----------------
__global__ __launch_bounds__(256) void ln_gates(const unsigned short* __restrict__ Zx,
                                                const unsigned short* __restrict__ Zh,
                                                const float* __restrict__ c0,
                                                const float* __restrict__ ax, const float* __restrict__ bx,
                                                const float* __restrict__ ah, const float* __restrict__ bh,
                                                const float* __restrict__ ac, const float* __restrict__ bc,
                                                float* __restrict__ out_top,
                                                unsigned short* __restrict__ hx_bf) {
  const int b = blockIdx.x;
  const int t = threadIdx.x;
  const int n = t * 8;
  const int w = t >> 6;
  const int lane = t & 63;
  const float inv_n = 1.0f / 2048.0f, inv_nm1 = 1.0f / 2047.0f;

  short8 zx[4], zh[4];
  const size_t rowoff = (size_t)b * NH4;
#pragma unroll
  for (int g = 0; g < 4; g++) {
    zx[g] = *(const short8*)(Zx + rowoff + g * NH + n);
    zh[g] = *(const short8*)(Zh + rowoff + g * NH + n);
  }

  float s[16];
#pragma unroll
  for (int g = 0; g < 4; g++) {
    float su = 0, sq = 0, su2 = 0, sq2 = 0;
#pragma unroll
    for (int j = 0; j < 8; j++) {
      float v = bf2f((unsigned short)zx[g][j]); su += v; sq += v * v;
      float u = bf2f((unsigned short)zh[g][j]); su2 += u; sq2 += u * u;
    }
    s[g * 4 + 0] = su; s[g * 4 + 1] = sq; s[g * 4 + 2] = su2; s[g * 4 + 3] = sq2;
  }
#pragma unroll
  for (int i = 0; i < 16; i++) {
    float v = s[i];
#pragma unroll
    for (int o = 32; o > 0; o >>= 1) v += __shfl_xor(v, o, 64);
    s[i] = v;
  }
  __shared__ float red[4][16];
  __shared__ float red2[4][2];
  if (lane == 0) {
#pragma unroll
    for (int i = 0; i < 16; i++) red[w][i] = s[i];
  }
  __syncthreads();
#pragma unroll
  for (int i = 0; i < 16; i++) s[i] = red[0][i] + red[1][i] + red[2][i] + red[3][i];

  float mux[4], ivx[4], muh[4], ivh[4];
#pragma unroll
  for (int g = 0; g < 4; g++) {
    mux[g] = s[g * 4 + 0] * inv_n;
    float vx = fmaxf((s[g * 4 + 1] - s[g * 4 + 0] * mux[g]) * inv_nm1, 0.0f);
    ivx[g] = 1.0f / (sqrtf(vx) + 1e-5f);
    muh[g] = s[g * 4 + 2] * inv_n;
    float vh = fmaxf((s[g * 4 + 3] - s[g * 4 + 2] * muh[g]) * inv_nm1, 0.0f);
    ivh[g] = 1.0f / (sqrtf(vh) + 1e-5f);
  }

  float axl[8], bxl[8], ahl[8], bhl[8], c0l[8];
  *(float4*)&axl[0] = *(const float4*)(ax + n); *(float4*)&axl[4] = *(const float4*)(ax + n + 4);
  *(float4*)&bxl[0] = *(const float4*)(bx + n); *(float4*)&bxl[4] = *(const float4*)(bx + n + 4);
  *(float4*)&ahl[0] = *(const float4*)(ah + n); *(float4*)&ahl[4] = *(const float4*)(ah + n + 4);
  *(float4*)&bhl[0] = *(const float4*)(bh + n); *(float4*)&bhl[4] = *(const float4*)(bh + n + 4);
  const float* c0p = c0 + (size_t)b * NH + n;
  *(float4*)&c0l[0] = *(const float4*)(c0p); *(float4*)&c0l[4] = *(const float4*)(c0p + 4);

  float cx[8], og[8];
  float cs = 0, css = 0;
#pragma unroll
  for (int j = 0; j < 8; j++) {
    float pre[4];
#pragma unroll
    for (int g = 0; g < 4; g++) {
      float vx = bf2f((unsigned short)zx[g][j]);
      float vh = bf2f((unsigned short)zh[g][j]);
      pre[g] = ((vx - mux[g]) * ivx[g]) * axl[j] + bxl[j]
             + ((vh - muh[g]) * ivh[g]) * ahl[j] + bhl[j];
    }
    float fg = sigf(pre[0]);
    float ig = sigf(pre[1]);
    float ct = tanh_f(pre[2]);
    og[j] = sigf(pre[3]);
    float c = fg * c0l[j] + ig * ct;
    cx[j] = c; cs += c; css += c * c;
  }
#pragma unroll
  for (int o = 32; o > 0; o >>= 1) { cs += __shfl_xor(cs, o, 64); css += __shfl_xor(css, o, 64); }
  if (lane == 0) { red2[w][0] = cs; red2[w][1] = css; }
  __syncthreads();
  cs = red2[0][0] + red2[1][0] + red2[2][0] + red2[3][0];
  css = red2[0][1] + red2[1][1] + red2[2][1] + red2[3][1];
  const float muc = cs * inv_n;
  const float varc = fmaxf((css - cs * muc) * inv_nm1, 0.0f);
  const float ivc = 1.0f / (sqrtf(varc) + 1e-5f);

  float acl[8], bcl[8];
  *(float4*)&acl[0] = *(const float4*)(ac + n); *(float4*)&acl[4] = *(const float4*)(ac + n + 4);
  *(float4*)&bcl[0] = *(const float4*)(bc + n); *(float4*)&bcl[4] = *(const float4*)(bc + n + 4);

  float hx[8];
#pragma unroll
  for (int j = 0; j < 8; j++)
    hx[j] = og[j] * tanh_f((cx[j] - muc) * ivc * acl[j] + bcl[j]);

  // outputs: d_out = [out(B,OUT) | hx(B,H) | cx(B,H)]
  float* hx_out = out_top + (size_t)NB * NOUT + (size_t)b * NH + n;
  float* cx_out = out_top + (size_t)NB * NOUT + (size_t)NB * NH + (size_t)b * NH + n;
  float4 v;
  v.x = hx[0]; v.y = hx[1]; v.z = hx[2]; v.w = hx[3]; *(float4*)(hx_out) = v;
  v.x = hx[4]; v.y = hx[5]; v.z = hx[6]; v.w = hx[7]; *(float4*)(hx_out + 4) = v;
  v.x = cx[0]; v.y = cx[1]; v.z = cx[2]; v.w = cx[3]; *(float4*)(cx_out) = v;
  v.x = cx[4]; v.y = cx[5]; v.z = cx[6]; v.w = cx[7]; *(float4*)(cx_out + 4) = v;
  ushort8v hb;
#pragma unroll
  for (int j = 0; j < 8; j++) hb[j] = f2bf(hx[j]);
  *(ushort8v*)(hx_bf + (size_t)b * NH + n) = hb;
}

extern "C" void kernel_launch(void* const* d_in, const int* in_sizes, int n_in,
                              void* d_out, int out_size, void* d_ws, size_t ws_size,
                              hipStream_t stream) {
  const float* inp = (const float*)d_in[0];
  const float* h0  = (const float*)d_in[1];
  const float* c0  = (const float*)d_in[2];
  // gate order f,i,c,o:  h-side W at 3,5,7,9 / b at 4,6,8,10; x-side W at 11..17 / b at 12..18
  const float* bhg[4] = {(const float*)d_in[4], (const float*)d_in[6], (const float*)d_in[8], (const float*)d_in[10]};
  const float* bxg[4] = {(const float*)d_in[12], (const float*)d_in[14], (const float*)d_in[16], (const float*)d_in[18]};
  const float* bdec = (const float*)d_in[20];
  const float* ax = (const float*)d_in[21];
  const float* bx = (const float*)d_in[22];
  const float* ah = (const float*)d_in[23];
  const float* bh = (const float*)d_in[24];
  const float* ac = (const float*)d_in[25];
  const float* bc = (const float*)d_in[26];

  unsigned short* wsb = (unsigned short*)d_ws;
  unsigned short* Xb   = wsb + OFF_XB;
  unsigned short* H0b  = wsb + OFF_H0B;
  unsigned short* HXb  = wsb + OFF_HXB;
  unsigned short* Wx4b = wsb + OFF_WX;
  unsigned short* Wh4b = wsb + OFF_WH;
  unsigned short* Wdb  = wsb + OFF_WD;
  unsigned short* Zx   = wsb + OFF_ZX;
  unsigned short* Zh   = wsb + OFF_ZH;

  // 1) one kernel converts all fp32 inputs/weights to bf16 workspace copies
  CvtArgs ca;
  ca.src[0] = inp; ca.src[1] = h0;
  ca.src[2] = (const float*)d_in[11]; ca.src[3] = (const float*)d_in[13];
  ca.src[4] = (const float*)d_in[15]; ca.src[5] = (const float*)d_in[17];
  ca.src[6] = (const float*)d_in[3];  ca.src[7] = (const float*)d_in[5];
  ca.src[8] = (const float*)d_in[7];  ca.src[9] = (const float*)d_in[9];
  ca.src[10] = (const float*)d_in[19];
  {
    const size_t nthr = CVT_TOTAL / 8;
    cvt_all<<<dim3((unsigned)((nthr + 255) / 256)), dim3(256), 0, stream>>>(ca, wsb);
  }

  // 2) Zx = inp @ Wx4^T + bx4 (K=1024) and Zh = h0 @ Wh4^T + bh4 (K=2048), one fused grid
  gemm_dual<<<dim3(NH4 / 128, NB / 128, 2), 256, 0, stream>>>(
      Xb, Wx4b, H0b, Wh4b,
      bxg[0], bxg[1], bxg[2], bxg[3],
      bhg[0], bhg[1], bhg[2], bhg[3],
      Zx, Zh);

  // 3) fused LN + gates -> hx, cx (fp32 into d_out) + hx bf16
  ln_gates<<<dim3(NB), 256, 0, stream>>>(Zx, Zh, c0, ax, bx, ah, bh, ac, bc, (float*)d_out, HXb);

  // 4) out = hx @ Wdec^T + bdec (M=4096, N=1024, K=2048), 64-row tiles -> 512 blocks
  gemm_dec<<<dim3(NOUT / 128, NB / 64), 256, 0, stream>>>(HXb, Wdb, bdec, (float*)d_out);
}

// Round 3
// 577.096 us; speedup vs baseline: 1.2113x; 1.0615x over previous
//
#include <hip/hip_runtime.h>

#define NB   4096
#define NIN  1024
#define NH   2048
#define NOUT 1024
#define NH4  8192   // 4*NH

typedef short short8 __attribute__((ext_vector_type(8)));
typedef float f32x4 __attribute__((ext_vector_type(4)));
typedef float f32x16 __attribute__((ext_vector_type(16)));
typedef unsigned short ushort8v __attribute__((ext_vector_type(8)));

__device__ __forceinline__ float bf2f(unsigned short u) {
  union { unsigned int i; float f; } c; c.i = ((unsigned int)u) << 16; return c.f;
}
__device__ __forceinline__ unsigned short f2bf(float f) {
  union { float f; unsigned int i; } c; c.f = f;
  unsigned int u = c.i;
  u += 0x7FFFu + ((u >> 16) & 1u);   // RNE; inputs are finite
  return (unsigned short)(u >> 16);
}
__device__ __forceinline__ float sigf(float x) { return 1.0f / (1.0f + __expf(-x)); }
__device__ __forceinline__ float tanh_f(float x) { return 1.0f - 2.0f / (__expf(2.0f * x) + 1.0f); }

// ---------------- workspace layout (ushort elems), compile-time ----------------
#define CNT_INP  ((size_t)NB * NIN)
#define CNT_H0   ((size_t)NB * NH)
#define CNT_WXG  ((size_t)NH * NIN)
#define CNT_WHG  ((size_t)NH * NH)
#define CNT_WD   ((size_t)NOUT * NH)
#define OFF_XB   ((size_t)0)
#define OFF_H0B  (OFF_XB + CNT_INP)
#define OFF_HXB  (OFF_H0B + CNT_H0)
#define OFF_WX   (OFF_HXB + CNT_H0)
#define OFF_WH   (OFF_WX + 4 * CNT_WXG)
#define OFF_WD   (OFF_WH + 4 * CNT_WHG)
#define OFF_ZX   (OFF_WD + CNT_WD)
#define OFF_ZH   (OFF_ZX + (size_t)NB * NH4)
#define CVT_TOTAL (OFF_WD + CNT_WD)

// ---------------- single fused fp32->bf16 convert over all 11 segments ----------------
struct CvtArgs { const float* src[11]; };

__global__ __launch_bounds__(256) void cvt_all(CvtArgs a, unsigned short* __restrict__ dstBase) {
  const size_t i = ((size_t)blockIdx.x * 256 + threadIdx.x) * 8;
  if (i >= CVT_TOTAL) return;
  const size_t cnt[11] = {CNT_INP, CNT_H0, CNT_WXG, CNT_WXG, CNT_WXG, CNT_WXG,
                          CNT_WHG, CNT_WHG, CNT_WHG, CNT_WHG, CNT_WD};
  const size_t dst[11] = {OFF_XB, OFF_H0B,
                          OFF_WX, OFF_WX + CNT_WXG, OFF_WX + 2 * CNT_WXG, OFF_WX + 3 * CNT_WXG,
                          OFF_WH, OFF_WH + CNT_WHG, OFF_WH + 2 * CNT_WHG, OFF_WH + 3 * CNT_WHG,
                          OFF_WD};
  size_t base = 0;
#pragma unroll
  for (int s = 0; s < 11; s++) {
    if (i < base + cnt[s]) {
      const size_t off = i - base;
      const float* sp = a.src[s] + off;
      float4 v0 = *(const float4*)(sp);
      float4 v1 = *(const float4*)(sp + 4);
      ushort8v o;
      o[0] = f2bf(v0.x); o[1] = f2bf(v0.y); o[2] = f2bf(v0.z); o[3] = f2bf(v0.w);
      o[4] = f2bf(v1.x); o[5] = f2bf(v1.y); o[6] = f2bf(v1.z); o[7] = f2bf(v1.w);
      *(ushort8v*)(dstBase + dst[s] + off) = o;
      return;
    }
    base += cnt[s];
  }
}

// ---------------- async global->LDS, 16B/lane ----------------
__device__ __forceinline__ void gload16(const void* g, void* l) {
  __builtin_amdgcn_global_load_lds((const __attribute__((address_space(1))) void*)g,
                                   (__attribute__((address_space(3))) void*)l, 16, 0, 0);
}

// ---------------- NT GEMM core, 32x32x16 MFMA, BK=64 ----------------
// C[m][n] = sum_k A[m][k]*B[n][k] + bias[n].  Block tile: (MT*64) x 128, 4 waves,
// wave tile (MT*32) x 64 as MT x 2 grid of 32x32 MFMA tiles.
// LDS rows are 64 elems (128 B = one bank wrap); 16B chunk b of row r stored at
// slot b ^ (r&7) -> every 8 consecutive lanes of a b128 fragment read cover all
// 32 banks exactly once (0 conflicts). Staging lane map: lane = (row&7)*8 + slot,
// global chunk = slot ^ (row&7)  (wave-uniform LDS base per global_load_lds rules;
// coalescing = 8 contiguous 128 B segments per issue).
// A/B frag: m(or n)=lane&31, k=(lane>>5)*8+i. C/D: col=lane&31,
// row=(reg&3)+8*(reg>>2)+4*(lane>>5)  [measured m74/m101].
template<int MT, bool BOUT>
__device__ __forceinline__ void gemm_core32(const unsigned short* __restrict__ A,
                                            const unsigned short* __restrict__ Bm,
                                            const float* b0p, const float* b1p,
                                            const float* b2p, const float* b3p,
                                            float* __restrict__ Cf, unsigned short* __restrict__ Cb,
                                            int N, int K) {
  constexpr int TM = MT * 64;
  __shared__ __align__(16) unsigned short As[TM * 64];
  __shared__ __align__(16) unsigned short Bs[128 * 64];
  const int t = threadIdx.x;
  const int w = t >> 6;
  const int lane = t & 63;
  const int r31 = lane & 31;
  const int hi = lane >> 5;
  const int rloc = lane >> 3;      // staging: row within 8-row issue group
  const int slot = lane & 7;       // staging: LDS slot within row
  const int bblk = slot ^ rloc;    // staging: global 16B k-block for this lane
  const int m0 = blockIdx.y * TM;
  const int n0 = blockIdx.x * 128;
  const int wm = (w >> 1) * (MT * 32);
  const int wn = (w & 1) * 64;

  f32x16 acc[MT][2];
#pragma unroll
  for (int i = 0; i < MT; i++)
#pragma unroll
    for (int j = 0; j < 2; j++)
#pragma unroll
      for (int r = 0; r < 16; r++) acc[i][j][r] = 0.f;

  // staging pointers: A has 2*MT issues/wave, B has 4 issues/wave; issue idx = w + 4*q
  const unsigned short* AgP[2 * MT];
  unsigned short* AsP[2 * MT];
#pragma unroll
  for (int q = 0; q < 2 * MT; q++) {
    const int iss = w + 4 * q;
    AgP[q] = A + (size_t)(m0 + iss * 8 + rloc) * K + bblk * 8;
    AsP[q] = As + iss * 512;
  }
  const unsigned short* BgP[4];
  unsigned short* BsP[4];
#pragma unroll
  for (int q = 0; q < 4; q++) {
    const int iss = w + 4 * q;
    BgP[q] = Bm + (size_t)(n0 + iss * 8 + rloc) * K + bblk * 8;
    BsP[q] = Bs + iss * 512;
  }

  const int swz = (r31 & 7);

  for (int k0 = 0; k0 < K; k0 += 64) {
#pragma unroll
    for (int q = 0; q < 2 * MT; q++) gload16(AgP[q] + k0, AsP[q]);
#pragma unroll
    for (int q = 0; q < 4; q++) gload16(BgP[q] + k0, BsP[q]);
    __syncthreads();

#pragma unroll
    for (int ks = 0; ks < 4; ks++) {
      const int phys = ((ks * 2 + hi) ^ swz) * 8;
      short8 af[MT], bf[2];
#pragma unroll
      for (int mt = 0; mt < MT; mt++) af[mt] = *(const short8*)&As[(wm + mt * 32 + r31) * 64 + phys];
#pragma unroll
      for (int jt = 0; jt < 2; jt++) bf[jt] = *(const short8*)&Bs[(wn + jt * 32 + r31) * 64 + phys];
#pragma unroll
      for (int mt = 0; mt < MT; mt++)
#pragma unroll
        for (int jt = 0; jt < 2; jt++)
          acc[mt][jt] = __builtin_amdgcn_mfma_f32_32x32x16_bf16(af[mt], bf[jt], acc[mt][jt], 0, 0, 0);
    }
    __syncthreads();
  }

  // epilogue
#pragma unroll
  for (int mt = 0; mt < MT; mt++) {
#pragma unroll
    for (int jt = 0; jt < 2; jt++) {
      const int col = n0 + wn + jt * 32 + r31;
      const float* bp = (col < 2048) ? b0p : ((col < 4096) ? b1p : ((col < 6144) ? b2p : b3p));
      const float bv = bp[col & 2047];
      const int rowb = m0 + wm + mt * 32 + hi * 4;
#pragma unroll
      for (int reg = 0; reg < 16; reg++) {
        const int row = rowb + (reg & 3) + 8 * (reg >> 2);
        const float v = acc[mt][jt][reg] + bv;
        const size_t idx = (size_t)row * N + col;
        if (BOUT) Cb[idx] = f2bf(v);
        else      Cf[idx] = v;
      }
    }
  }
}

// Zx and Zh fused in one grid (z=0: x-side K=1024, z=1: h-side K=2048).
__global__ __launch_bounds__(256) void gemm_dual(const unsigned short* __restrict__ Xb,
                                                 const unsigned short* __restrict__ Wx,
                                                 const unsigned short* __restrict__ H0b,
                                                 const unsigned short* __restrict__ Wh,
                                                 const float* bx0, const float* bx1,
                                                 const float* bx2, const float* bx3,
                                                 const float* bh0, const float* bh1,
                                                 const float* bh2, const float* bh3,
                                                 unsigned short* __restrict__ Zx,
                                                 unsigned short* __restrict__ Zh) {
  if (blockIdx.z == 0)
    gemm_core32<2, true>(Xb, Wx, bx0, bx1, bx2, bx3, nullptr, Zx, NH4, NIN);
  else
    gemm_core32<2, true>(H0b, Wh, bh0, bh1, bh2, bh3, nullptr, Zh, NH4, NH);
}

// decoder: 64x128 tile -> 512 blocks (2/CU)
__global__ __launch_bounds__(256) void gemm_dec(const unsigned short* __restrict__ HXb,
                                                const unsigned short* __restrict__ Wd,
                                                const float* __restrict__ bdec,
                                                float* __restrict__ out) {
  gemm_core32<1, false>(HXb, Wd, bdec, bdec, bdec, bdec, out, nullptr, NOUT, NH);
}

// ---------------- fused LN(zx)+LN(zh) -> gates -> cx -> LN(cx) -> hx ----------------
__global__ __launch_bounds__(256) void ln_gates(const unsigned short* __restrict__ Zx,
                                                const unsigned short* __restrict__ Zh,
                                                const float* __restrict__ c0,
                                                const float* __restrict__ ax, const float* __restrict__ bx,
                                                const float* __restrict__ ah, const float* __restrict__ bh,
                                                const float* __restrict__ ac, const float* __restrict__ bc,
                                                float* __restrict__ out_top,
                                                unsigned short* __restrict__ hx_bf) {
  const int b = blockIdx.x;
  const int t = threadIdx.x;
  const int n = t * 8;
  const int w = t >> 6;
  const int lane = t & 63;
  const float inv_n = 1.0f / 2048.0f, inv_nm1 = 1.0f / 2047.0f;

  short8 zx[4], zh[4];
  const size_t rowoff = (size_t)b * NH4;
#pragma unroll
  for (int g = 0; g < 4; g++) {
    zx[g] = *(const short8*)(Zx + rowoff + g * NH + n);
    zh[g] = *(const short8*)(Zh + rowoff + g * NH + n);
  }

  float s[16];
#pragma unroll
  for (int g = 0; g < 4; g++) {
    float su = 0, sq = 0, su2 = 0, sq2 = 0;
#pragma unroll
    for (int j = 0; j < 8; j++) {
      float v = bf2f((unsigned short)zx[g][j]); su += v; sq += v * v;
      float u = bf2f((unsigned short)zh[g][j]); su2 += u; sq2 += u * u;
    }
    s[g * 4 + 0] = su; s[g * 4 + 1] = sq; s[g * 4 + 2] = su2; s[g * 4 + 3] = sq2;
  }
#pragma unroll
  for (int i = 0; i < 16; i++) {
    float v = s[i];
#pragma unroll
    for (int o = 32; o > 0; o >>= 1) v += __shfl_xor(v, o, 64);
    s[i] = v;
  }
  __shared__ float red[4][16];
  __shared__ float red2[4][2];
  if (lane == 0) {
#pragma unroll
    for (int i = 0; i < 16; i++) red[w][i] = s[i];
  }
  __syncthreads();
#pragma unroll
  for (int i = 0; i < 16; i++) s[i] = red[0][i] + red[1][i] + red[2][i] + red[3][i];

  float mux[4], ivx[4], muh[4], ivh[4];
#pragma unroll
  for (int g = 0; g < 4; g++) {
    mux[g] = s[g * 4 + 0] * inv_n;
    float vx = fmaxf((s[g * 4 + 1] - s[g * 4 + 0] * mux[g]) * inv_nm1, 0.0f);
    ivx[g] = 1.0f / (sqrtf(vx) + 1e-5f);
    muh[g] = s[g * 4 + 2] * inv_n;
    float vh = fmaxf((s[g * 4 + 3] - s[g * 4 + 2] * muh[g]) * inv_nm1, 0.0f);
    ivh[g] = 1.0f / (sqrtf(vh) + 1e-5f);
  }

  float axl[8], bxl[8], ahl[8], bhl[8], c0l[8];
  *(float4*)&axl[0] = *(const float4*)(ax + n); *(float4*)&axl[4] = *(const float4*)(ax + n + 4);
  *(float4*)&bxl[0] = *(const float4*)(bx + n); *(float4*)&bxl[4] = *(const float4*)(bx + n + 4);
  *(float4*)&ahl[0] = *(const float4*)(ah + n); *(float4*)&ahl[4] = *(const float4*)(ah + n + 4);
  *(float4*)&bhl[0] = *(const float4*)(bh + n); *(float4*)&bhl[4] = *(const float4*)(bh + n + 4);
  const float* c0p = c0 + (size_t)b * NH + n;
  *(float4*)&c0l[0] = *(const float4*)(c0p); *(float4*)&c0l[4] = *(const float4*)(c0p + 4);

  float cx[8], og[8];
  float cs = 0, css = 0;
#pragma unroll
  for (int j = 0; j < 8; j++) {
    float pre[4];
#pragma unroll
    for (int g = 0; g < 4; g++) {
      float vx = bf2f((unsigned short)zx[g][j]);
      float vh = bf2f((unsigned short)zh[g][j]);
      pre[g] = ((vx - mux[g]) * ivx[g]) * axl[j] + bxl[j]
             + ((vh - muh[g]) * ivh[g]) * ahl[j] + bhl[j];
    }
    float fg = sigf(pre[0]);
    float ig = sigf(pre[1]);
    float ct = tanh_f(pre[2]);
    og[j] = sigf(pre[3]);
    float c = fg * c0l[j] + ig * ct;
    cx[j] = c; cs += c; css += c * c;
  }
#pragma unroll
  for (int o = 32; o > 0; o >>= 1) { cs += __shfl_xor(cs, o, 64); css += __shfl_xor(css, o, 64); }
  if (lane == 0) { red2[w][0] = cs; red2[w][1] = css; }
  __syncthreads();
  cs = red2[0][0] + red2[1][0] + red2[2][0] + red2[3][0];
  css = red2[0][1] + red2[1][1] + red2[2][1] + red2[3][1];
  const float muc = cs * inv_n;
  const float varc = fmaxf((css - cs * muc) * inv_nm1, 0.0f);
  const float ivc = 1.0f / (sqrtf(varc) + 1e-5f);

  float acl[8], bcl[8];
  *(float4*)&acl[0] = *(const float4*)(ac + n); *(float4*)&acl[4] = *(const float4*)(ac + n + 4);
  *(float4*)&bcl[0] = *(const float4*)(bc + n); *(float4*)&bcl[4] = *(const float4*)(bc + n + 4);

  float hx[8];
#pragma unroll
  for (int j = 0; j < 8; j++)
    hx[j] = og[j] * tanh_f((cx[j] - muc) * ivc * acl[j] + bcl[j]);

  // outputs: d_out = [out(B,OUT) | hx(B,H) | cx(B,H)]
  float* hx_out = out_top + (size_t)NB * NOUT + (size_t)b * NH + n;
  float* cx_out = out_top + (size_t)NB * NOUT + (size_t)NB * NH + (size_t)b * NH + n;
  float4 v;
  v.x = hx[0]; v.y = hx[1]; v.z = hx[2]; v.w = hx[3]; *(float4*)(hx_out) = v;
  v.x = hx[4]; v.y = hx[5]; v.z = hx[6]; v.w = hx[7]; *(float4*)(hx_out + 4) = v;
  v.x = cx[0]; v.y = cx[1]; v.z = cx[2]; v.w = cx[3]; *(float4*)(cx_out) = v;
  v.x = cx[4]; v.y = cx[5]; v.z = cx[6]; v.w = cx[7]; *(float4*)(cx_out + 4) = v;
  ushort8v hb;
#pragma unroll
  for (int j = 0; j < 8; j++) hb[j] = f2bf(hx[j]);
  *(ushort8v*)(hx_bf + (size_t)b * NH + n) = hb;
}

extern "C" void kernel_launch(void* const* d_in, const int* in_sizes, int n_in,
                              void* d_out, int out_size, void* d_ws, size_t ws_size,
                              hipStream_t stream) {
  const float* inp = (const float*)d_in[0];
  const float* h0  = (const float*)d_in[1];
  const float* c0  = (const float*)d_in[2];
  const float* bhg[4] = {(const float*)d_in[4], (const float*)d_in[6], (const float*)d_in[8], (const float*)d_in[10]};
  const float* bxg[4] = {(const float*)d_in[12], (const float*)d_in[14], (const float*)d_in[16], (const float*)d_in[18]};
  const float* bdec = (const float*)d_in[20];
  const float* ax = (const float*)d_in[21];
  const float* bx = (const float*)d_in[22];
  const float* ah = (const float*)d_in[23];
  const float* bh = (const float*)d_in[24];
  const float* ac = (const float*)d_in[25];
  const float* bc = (const float*)d_in[26];

  unsigned short* wsb = (unsigned short*)d_ws;
  unsigned short* Xb   = wsb + OFF_XB;
  unsigned short* H0b  = wsb + OFF_H0B;
  unsigned short* HXb  = wsb + OFF_HXB;
  unsigned short* Wx4b = wsb + OFF_WX;
  unsigned short* Wh4b = wsb + OFF_WH;
  unsigned short* Wdb  = wsb + OFF_WD;
  unsigned short* Zx   = wsb + OFF_ZX;
  unsigned short* Zh   = wsb + OFF_ZH;

  CvtArgs ca;
  ca.src[0] = inp; ca.src[1] = h0;
  ca.src[2] = (const float*)d_in[11]; ca.src[3] = (const float*)d_in[13];
  ca.src[4] = (const float*)d_in[15]; ca.src[5] = (const float*)d_in[17];
  ca.src[6] = (const float*)d_in[3];  ca.src[7] = (const float*)d_in[5];
  ca.src[8] = (const float*)d_in[7];  ca.src[9] = (const float*)d_in[9];
  ca.src[10] = (const float*)d_in[19];
  {
    const size_t nthr = CVT_TOTAL / 8;
    cvt_all<<<dim3((unsigned)((nthr + 255) / 256)), dim3(256), 0, stream>>>(ca, wsb);
  }

  gemm_dual<<<dim3(NH4 / 128, NB / 128, 2), 256, 0, stream>>>(
      Xb, Wx4b, H0b, Wh4b,
      bxg[0], bxg[1], bxg[2], bxg[3],
      bhg[0], bhg[1], bhg[2], bhg[3],
      Zx, Zh);

  ln_gates<<<dim3(NB), 256, 0, stream>>>(Zx, Zh, c0, ax, bx, ah, bh, ac, bc, (float*)d_out, HXb);

  gemm_dec<<<dim3(NOUT / 128, NB / 64), 256, 0, stream>>>(HXb, Wdb, bdec, (float*)d_out);
}

// Round 4
// 564.479 us; speedup vs baseline: 1.2384x; 1.0224x over previous
//
#include <hip/hip_runtime.h>

#define NB   4096
#define NIN  1024
#define NH   2048
#define NOUT 1024
#define NH4  8192   // 4*NH

typedef short short8 __attribute__((ext_vector_type(8)));
typedef float f32x4 __attribute__((ext_vector_type(4)));
typedef float f32x16 __attribute__((ext_vector_type(16)));
typedef unsigned short ushort8v __attribute__((ext_vector_type(8)));

__device__ __forceinline__ float bf2f(unsigned short u) {
  union { unsigned int i; float f; } c; c.i = ((unsigned int)u) << 16; return c.f;
}
__device__ __forceinline__ unsigned short f2bf(float f) {
  union { float f; unsigned int i; } c; c.f = f;
  unsigned int u = c.i;
  u += 0x7FFFu + ((u >> 16) & 1u);   // RNE; inputs are finite
  return (unsigned short)(u >> 16);
}
__device__ __forceinline__ float sigf(float x) { return 1.0f / (1.0f + __expf(-x)); }
__device__ __forceinline__ float tanh_f(float x) { return 1.0f - 2.0f / (__expf(2.0f * x) + 1.0f); }

// ---------------- workspace layout (ushort elems), compile-time ----------------
#define CNT_INP  ((size_t)NB * NIN)
#define CNT_H0   ((size_t)NB * NH)
#define CNT_WXG  ((size_t)NH * NIN)
#define CNT_WHG  ((size_t)NH * NH)
#define CNT_WD   ((size_t)NOUT * NH)
#define OFF_XB   ((size_t)0)
#define OFF_H0B  (OFF_XB + CNT_INP)
#define OFF_HXB  (OFF_H0B + CNT_H0)
#define OFF_WX   (OFF_HXB + CNT_H0)
#define OFF_WH   (OFF_WX + 4 * CNT_WXG)
#define OFF_WD   (OFF_WH + 4 * CNT_WHG)
#define OFF_ZX   (OFF_WD + CNT_WD)
#define OFF_ZH   (OFF_ZX + (size_t)NB * NH4)
#define CVT_TOTAL (OFF_WD + CNT_WD)

// ---------------- single fused fp32->bf16 convert over all 11 segments ----------------
struct CvtArgs { const float* src[11]; };

__global__ __launch_bounds__(256) void cvt_all(CvtArgs a, unsigned short* __restrict__ dstBase) {
  const size_t i = ((size_t)blockIdx.x * 256 + threadIdx.x) * 8;
  if (i >= CVT_TOTAL) return;
  const size_t cnt[11] = {CNT_INP, CNT_H0, CNT_WXG, CNT_WXG, CNT_WXG, CNT_WXG,
                          CNT_WHG, CNT_WHG, CNT_WHG, CNT_WHG, CNT_WD};
  const size_t dst[11] = {OFF_XB, OFF_H0B,
                          OFF_WX, OFF_WX + CNT_WXG, OFF_WX + 2 * CNT_WXG, OFF_WX + 3 * CNT_WXG,
                          OFF_WH, OFF_WH + CNT_WHG, OFF_WH + 2 * CNT_WHG, OFF_WH + 3 * CNT_WHG,
                          OFF_WD};
  size_t base = 0;
#pragma unroll
  for (int s = 0; s < 11; s++) {
    if (i < base + cnt[s]) {
      const size_t off = i - base;
      const float* sp = a.src[s] + off;
      float4 v0 = *(const float4*)(sp);
      float4 v1 = *(const float4*)(sp + 4);
      ushort8v o;
      o[0] = f2bf(v0.x); o[1] = f2bf(v0.y); o[2] = f2bf(v0.z); o[3] = f2bf(v0.w);
      o[4] = f2bf(v1.x); o[5] = f2bf(v1.y); o[6] = f2bf(v1.z); o[7] = f2bf(v1.w);
      *(ushort8v*)(dstBase + dst[s] + off) = o;
      return;
    }
    base += cnt[s];
  }
}

// ---------------- async global->LDS, 16B/lane ----------------
__device__ __forceinline__ void gload16(const void* g, void* l) {
  __builtin_amdgcn_global_load_lds((const __attribute__((address_space(1))) void*)g,
                                   (__attribute__((address_space(3))) void*)l, 16, 0, 0);
}

// ---------------- NT GEMM core, 32x32x16 MFMA, BK=64 ----------------
// LDS rows = 64 elems (128 B). Swizzle: 16B chunk c of row r stored at slot
// c ^ swz(r), swz(r) = (r&7) ^ ((r>>3)&3).  Evidence-driven (R2 vs R3 counters):
// conflict unit behaves like lane groups {l, l+8, ...}; rows congruent mod 8 must
// get distinct slots, else 4-way (+4 cyc/b128, measured R3). This swz gives
// consecutive-8 groups 8 distinct slots and mod-8 row sets distinct slots (<=2-way,
// free per m136). Tile offsets (mult. of 32) don't affect swz bits.
// Staging: lane (rloc=lane>>3, slot=lane&7) of issue iss fetches global chunk
// slot ^ rloc ^ (iss&3)  (LDS dest = wave-uniform base + lane*16; still 8
// contiguous 128 B segments per issue -> coalescing unchanged).
// A/B frag: m(n)=lane&31, k=(lane>>5)*8+i. C/D: col=lane&31,
// row=(reg&3)+8*(reg>>2)+4*(lane>>5)  [measured m74/m101].
template<int MT, bool BOUT>
__device__ __forceinline__ void gemm_core32(const unsigned short* __restrict__ A,
                                            const unsigned short* __restrict__ Bm,
                                            const float* b0p, const float* b1p,
                                            const float* b2p, const float* b3p,
                                            float* __restrict__ Cf, unsigned short* __restrict__ Cb,
                                            int N, int K) {
  constexpr int TM = MT * 64;
  __shared__ __align__(16) unsigned short As[TM * 64];
  __shared__ __align__(16) unsigned short Bs[128 * 64];
  const int t = threadIdx.x;
  const int w = t >> 6;
  const int lane = t & 63;
  const int r31 = lane & 31;
  const int hi = lane >> 5;
  const int rloc = lane >> 3;      // staging: row within 8-row issue group
  const int slot = lane & 7;       // staging: LDS slot within row
  const int m0 = blockIdx.y * TM;
  const int n0 = blockIdx.x * 128;
  const int wm = (w >> 1) * (MT * 32);
  const int wn = (w & 1) * 64;

  f32x16 acc[MT][2];
#pragma unroll
  for (int i = 0; i < MT; i++)
#pragma unroll
    for (int j = 0; j < 2; j++)
#pragma unroll
      for (int r = 0; r < 16; r++) acc[i][j][r] = 0.f;

  // staging pointers: A has 2*MT issues/wave, B has 4 issues/wave; issue idx = w + 4*q
  const unsigned short* AgP[2 * MT];
  unsigned short* AsP[2 * MT];
#pragma unroll
  for (int q = 0; q < 2 * MT; q++) {
    const int iss = w + 4 * q;
    const int bblk = slot ^ rloc ^ (iss & 3);   // global 16B k-block for this lane
    AgP[q] = A + (size_t)(m0 + iss * 8 + rloc) * K + bblk * 8;
    AsP[q] = As + iss * 512;
  }
  const unsigned short* BgP[4];
  unsigned short* BsP[4];
#pragma unroll
  for (int q = 0; q < 4; q++) {
    const int iss = w + 4 * q;
    const int bblk = slot ^ rloc ^ (iss & 3);
    BgP[q] = Bm + (size_t)(n0 + iss * 8 + rloc) * K + bblk * 8;
    BsP[q] = Bs + iss * 512;
  }

  const int swz = (r31 & 7) ^ ((r31 >> 3) & 3);

  for (int k0 = 0; k0 < K; k0 += 64) {
#pragma unroll
    for (int q = 0; q < 2 * MT; q++) gload16(AgP[q] + k0, AsP[q]);
#pragma unroll
    for (int q = 0; q < 4; q++) gload16(BgP[q] + k0, BsP[q]);
    __syncthreads();

#pragma unroll
    for (int ks = 0; ks < 4; ks++) {
      const int phys = ((ks * 2 + hi) ^ swz) * 8;
      short8 af[MT], bf[2];
#pragma unroll
      for (int mt = 0; mt < MT; mt++) af[mt] = *(const short8*)&As[(wm + mt * 32 + r31) * 64 + phys];
#pragma unroll
      for (int jt = 0; jt < 2; jt++) bf[jt] = *(const short8*)&Bs[(wn + jt * 32 + r31) * 64 + phys];
#pragma unroll
      for (int mt = 0; mt < MT; mt++)
#pragma unroll
        for (int jt = 0; jt < 2; jt++)
          acc[mt][jt] = __builtin_amdgcn_mfma_f32_32x32x16_bf16(af[mt], bf[jt], acc[mt][jt], 0, 0, 0);
    }
    __syncthreads();
  }

  // epilogue
#pragma unroll
  for (int mt = 0; mt < MT; mt++) {
#pragma unroll
    for (int jt = 0; jt < 2; jt++) {
      const int col = n0 + wn + jt * 32 + r31;
      const float* bp = (col < 2048) ? b0p : ((col < 4096) ? b1p : ((col < 6144) ? b2p : b3p));
      const float bv = bp[col & 2047];
      const int rowb = m0 + wm + mt * 32 + hi * 4;
#pragma unroll
      for (int reg = 0; reg < 16; reg++) {
        const int row = rowb + (reg & 3) + 8 * (reg >> 2);
        const float v = acc[mt][jt][reg] + bv;
        const size_t idx = (size_t)row * N + col;
        if (BOUT) Cb[idx] = f2bf(v);
        else      Cf[idx] = v;
      }
    }
  }
}

// Zx and Zh fused in one grid (z=0: x-side K=1024, z=1: h-side K=2048).
__global__ __launch_bounds__(256) void gemm_dual(const unsigned short* __restrict__ Xb,
                                                 const unsigned short* __restrict__ Wx,
                                                 const unsigned short* __restrict__ H0b,
                                                 const unsigned short* __restrict__ Wh,
                                                 const float* bx0, const float* bx1,
                                                 const float* bx2, const float* bx3,
                                                 const float* bh0, const float* bh1,
                                                 const float* bh2, const float* bh3,
                                                 unsigned short* __restrict__ Zx,
                                                 unsigned short* __restrict__ Zh) {
  if (blockIdx.z == 0)
    gemm_core32<2, true>(Xb, Wx, bx0, bx1, bx2, bx3, nullptr, Zx, NH4, NIN);
  else
    gemm_core32<2, true>(H0b, Wh, bh0, bh1, bh2, bh3, nullptr, Zh, NH4, NH);
}

// decoder: 64x128 tile -> 512 blocks (2/CU)
__global__ __launch_bounds__(256) void gemm_dec(const unsigned short* __restrict__ HXb,
                                                const unsigned short* __restrict__ Wd,
                                                const float* __restrict__ bdec,
                                                float* __restrict__ out) {
  gemm_core32<1, false>(HXb, Wd, bdec, bdec, bdec, bdec, out, nullptr, NOUT, NH);
}

// ---------------- fused LN(zx)+LN(zh) -> gates -> cx -> LN(cx) -> hx ----------------
__global__ __launch_bounds__(256) void ln_gates(const unsigned short* __restrict__ Zx,
                                                const unsigned short* __restrict__ Zh,
                                                const float* __restrict__ c0,
                                                const float* __restrict__ ax, const float* __restrict__ bx,
                                                const float* __restrict__ ah, const float* __restrict__ bh,
                                                const float* __restrict__ ac, const float* __restrict__ bc,
                                                float* __restrict__ out_top,
                                                unsigned short* __restrict__ hx_bf) {
  const int b = blockIdx.x;
  const int t = threadIdx.x;
  const int n = t * 8;
  const int w = t >> 6;
  const int lane = t & 63;
  const float inv_n = 1.0f / 2048.0f, inv_nm1 = 1.0f / 2047.0f;

  short8 zx[4], zh[4];
  const size_t rowoff = (size_t)b * NH4;
#pragma unroll
  for (int g = 0; g < 4; g++) {
    zx[g] = *(const short8*)(Zx + rowoff + g * NH + n);
    zh[g] = *(const short8*)(Zh + rowoff + g * NH + n);
  }

  float s[16];
#pragma unroll
  for (int g = 0; g < 4; g++) {
    float su = 0, sq = 0, su2 = 0, sq2 = 0;
#pragma unroll
    for (int j = 0; j < 8; j++) {
      float v = bf2f((unsigned short)zx[g][j]); su += v; sq += v * v;
      float u = bf2f((unsigned short)zh[g][j]); su2 += u; sq2 += u * u;
    }
    s[g * 4 + 0] = su; s[g * 4 + 1] = sq; s[g * 4 + 2] = su2; s[g * 4 + 3] = sq2;
  }
#pragma unroll
  for (int i = 0; i < 16; i++) {
    float v = s[i];
#pragma unroll
    for (int o = 32; o > 0; o >>= 1) v += __shfl_xor(v, o, 64);
    s[i] = v;
  }
  __shared__ float red[4][16];
  __shared__ float red2[4][2];
  if (lane == 0) {
#pragma unroll
    for (int i = 0; i < 16; i++) red[w][i] = s[i];
  }
  __syncthreads();
#pragma unroll
  for (int i = 0; i < 16; i++) s[i] = red[0][i] + red[1][i] + red[2][i] + red[3][i];

  float mux[4], ivx[4], muh[4], ivh[4];
#pragma unroll
  for (int g = 0; g < 4; g++) {
    mux[g] = s[g * 4 + 0] * inv_n;
    float vx = fmaxf((s[g * 4 + 1] - s[g * 4 + 0] * mux[g]) * inv_nm1, 0.0f);
    ivx[g] = 1.0f / (sqrtf(vx) + 1e-5f);
    muh[g] = s[g * 4 + 2] * inv_n;
    float vh = fmaxf((s[g * 4 + 3] - s[g * 4 + 2] * muh[g]) * inv_nm1, 0.0f);
    ivh[g] = 1.0f / (sqrtf(vh) + 1e-5f);
  }

  float axl[8], bxl[8], ahl[8], bhl[8], c0l[8];
  *(float4*)&axl[0] = *(const float4*)(ax + n); *(float4*)&axl[4] = *(const float4*)(ax + n + 4);
  *(float4*)&bxl[0] = *(const float4*)(bx + n); *(float4*)&bxl[4] = *(const float4*)(bx + n + 4);
  *(float4*)&ahl[0] = *(const float4*)(ah + n); *(float4*)&ahl[4] = *(const float4*)(ah + n + 4);
  *(float4*)&bhl[0] = *(const float4*)(bh + n); *(float4*)&bhl[4] = *(const float4*)(bh + n + 4);
  const float* c0p = c0 + (size_t)b * NH + n;
  *(float4*)&c0l[0] = *(const float4*)(c0p); *(float4*)&c0l[4] = *(const float4*)(c0p + 4);

  float cx[8], og[8];
  float cs = 0, css = 0;
#pragma unroll
  for (int j = 0; j < 8; j++) {
    float pre[4];
#pragma unroll
    for (int g = 0; g < 4; g++) {
      float vx = bf2f((unsigned short)zx[g][j]);
      float vh = bf2f((unsigned short)zh[g][j]);
      pre[g] = ((vx - mux[g]) * ivx[g]) * axl[j] + bxl[j]
             + ((vh - muh[g]) * ivh[g]) * ahl[j] + bhl[j];
    }
    float fg = sigf(pre[0]);
    float ig = sigf(pre[1]);
    float ct = tanh_f(pre[2]);
    og[j] = sigf(pre[3]);
    float c = fg * c0l[j] + ig * ct;
    cx[j] = c; cs += c; css += c * c;
  }
#pragma unroll
  for (int o = 32; o > 0; o >>= 1) { cs += __shfl_xor(cs, o, 64); css += __shfl_xor(css, o, 64); }
  if (lane == 0) { red2[w][0] = cs; red2[w][1] = css; }
  __syncthreads();
  cs = red2[0][0] + red2[1][0] + red2[2][0] + red2[3][0];
  css = red2[0][1] + red2[1][1] + red2[2][1] + red2[3][1];
  const float muc = cs * inv_n;
  const float varc = fmaxf((css - cs * muc) * inv_nm1, 0.0f);
  const float ivc = 1.0f / (sqrtf(varc) + 1e-5f);

  float acl[8], bcl[8];
  *(float4*)&acl[0] = *(const float4*)(ac + n); *(float4*)&acl[4] = *(const float4*)(ac + n + 4);
  *(float4*)&bcl[0] = *(const float4*)(bc + n); *(float4*)&bcl[4] = *(const float4*)(bc + n + 4);

  float hx[8];
#pragma unroll
  for (int j = 0; j < 8; j++)
    hx[j] = og[j] * tanh_f((cx[j] - muc) * ivc * acl[j] + bcl[j]);

  // outputs: d_out = [out(B,OUT) | hx(B,H) | cx(B,H)]
  float* hx_out = out_top + (size_t)NB * NOUT + (size_t)b * NH + n;
  float* cx_out = out_top + (size_t)NB * NOUT + (size_t)NB * NH + (size_t)b * NH + n;
  float4 v;
  v.x = hx[0]; v.y = hx[1]; v.z = hx[2]; v.w = hx[3]; *(float4*)(hx_out) = v;
  v.x = hx[4]; v.y = hx[5]; v.z = hx[6]; v.w = hx[7]; *(float4*)(hx_out + 4) = v;
  v.x = cx[0]; v.y = cx[1]; v.z = cx[2]; v.w = cx[3]; *(float4*)(cx_out) = v;
  v.x = cx[4]; v.y = cx[5]; v.z = cx[6]; v.w = cx[7]; *(float4*)(cx_out + 4) = v;
  ushort8v hb;
#pragma unroll
  for (int j = 0; j < 8; j++) hb[j] = f2bf(hx[j]);
  *(ushort8v*)(hx_bf + (size_t)b * NH + n) = hb;
}

extern "C" void kernel_launch(void* const* d_in, const int* in_sizes, int n_in,
                              void* d_out, int out_size, void* d_ws, size_t ws_size,
                              hipStream_t stream) {
  const float* inp = (const float*)d_in[0];
  const float* h0  = (const float*)d_in[1];
  const float* c0  = (const float*)d_in[2];
  const float* bhg[4] = {(const float*)d_in[4], (const float*)d_in[6], (const float*)d_in[8], (const float*)d_in[10]};
  const float* bxg[4] = {(const float*)d_in[12], (const float*)d_in[14], (const float*)d_in[16], (const float*)d_in[18]};
  const float* bdec = (const float*)d_in[20];
  const float* ax = (const float*)d_in[21];
  const float* bx = (const float*)d_in[22];
  const float* ah = (const float*)d_in[23];
  const float* bh = (const float*)d_in[24];
  const float* ac = (const float*)d_in[25];
  const float* bc = (const float*)d_in[26];

  unsigned short* wsb = (unsigned short*)d_ws;
  unsigned short* Xb   = wsb + OFF_XB;
  unsigned short* H0b  = wsb + OFF_H0B;
  unsigned short* HXb  = wsb + OFF_HXB;
  unsigned short* Wx4b = wsb + OFF_WX;
  unsigned short* Wh4b = wsb + OFF_WH;
  unsigned short* Wdb  = wsb + OFF_WD;
  unsigned short* Zx   = wsb + OFF_ZX;
  unsigned short* Zh   = wsb + OFF_ZH;

  CvtArgs ca;
  ca.src[0] = inp; ca.src[1] = h0;
  ca.src[2] = (const float*)d_in[11]; ca.src[3] = (const float*)d_in[13];
  ca.src[4] = (const float*)d_in[15]; ca.src[5] = (const float*)d_in[17];
  ca.src[6] = (const float*)d_in[3];  ca.src[7] = (const float*)d_in[5];
  ca.src[8] = (const float*)d_in[7];  ca.src[9] = (const float*)d_in[9];
  ca.src[10] = (const float*)d_in[19];
  {
    const size_t nthr = CVT_TOTAL / 8;
    cvt_all<<<dim3((unsigned)((nthr + 255) / 256)), dim3(256), 0, stream>>>(ca, wsb);
  }

  gemm_dual<<<dim3(NH4 / 128, NB / 128, 2), 256, 0, stream>>>(
      Xb, Wx4b, H0b, Wh4b,
      bxg[0], bxg[1], bxg[2], bxg[3],
      bhg[0], bhg[1], bhg[2], bhg[3],
      Zx, Zh);

  ln_gates<<<dim3(NB), 256, 0, stream>>>(Zx, Zh, c0, ax, bx, ah, bh, ac, bc, (float*)d_out, HXb);

  gemm_dec<<<dim3(NOUT / 128, NB / 64), 256, 0, stream>>>(HXb, Wdb, bdec, (float*)d_out);
}